// Round 6
// baseline (259.347 us; speedup 1.0000x reference)
//
#include <hip/hip_runtime.h>

// PatchEmbedding2 on MI355X — round 13.
// r12 post-mortem: barrier-halving null (225.3 vs 224.8) — gemm plateaued
// ~55us across 4 structural levers (r9-r12). Budget: fills 118 (fixed),
// gemm 55, gather 25, prep 5, gaps ~20. New lever: FUSE gather into gemm
// A-staging (T14 reg-staging): gemm loads gathered f32 x-patches directly
// (2x float4 per 16B chunk via prep-built rowBase/rowMask tables), converts
// f32->bf16 in-register (same RNE f2bf), ds_write_b128 to the SAME swizzled
// LDS slots gll used (write slot c^lrow, read ^r7 — r8-verified involution,
// read path untouched). Ab workspace + gather kernel deleted (-25us, -150MB
// HBM). x (101MB) is L3-resident; 6 col-blocks per A-panel are XCD-adjacent
// -> L2 re-reads. B stays gll. Schedule: tile t ph0 issues B-gll(t+1) then
// A-loads(t+1); ph1 converts+writes (dep-wait subsumes B drain; vmcnt(0)
// backstop pre-barrier ~free). Ledger: prologue stages tile0; t stages t+1;
// tail 45->46, 46->47, 47 bare. Geometry unchanged: BM192 BN128 BK64, 8
// waves, 3-buf (120KB), 252 blocks=1/CU, XCD swizzle, setprio MFMA.

typedef __attribute__((ext_vector_type(8))) short bf16x8;
typedef __attribute__((ext_vector_type(4))) float f32x4;

#define K_DIM 3072
#define N_DIM 768
#define BM 192
#define BN 128

__device__ __forceinline__ unsigned short f2bf(float f) {
  unsigned int u = __float_as_uint(f);
  u += 0x7fffu + ((u >> 16) & 1u);   // RNE
  return (unsigned short)(u >> 16);
}

__device__ __forceinline__ unsigned int pk2(float a, float b) {
  return (unsigned int)f2bf(a) | ((unsigned int)f2bf(b) << 16);
}

__device__ __forceinline__ void gload16(const void* g, void* l) {
  __builtin_amdgcn_global_load_lds(
      (const __attribute__((address_space(1))) void*)g,
      (__attribute__((address_space(3))) void*)l, 16, 0, 0);
}

// ---------------- prep: wconv (row-major) + layout + row tables --------------
__global__ __launch_bounds__(1024)
void prep_kernel(const float* __restrict__ W, unsigned short* __restrict__ Wb, int w4,
                 const float* __restrict__ iw, int P,
                 int* __restrict__ tokBase, int* __restrict__ tokMask,
                 int* __restrict__ rowBase, int* __restrict__ rowMask,
                 int nB, int Mpad, int NB_W) {
  int bid = blockIdx.x;
  int tid = threadIdx.x;
  if (bid < NB_W) {
    int idx = bid * 1024 + tid;
    if (idx < w4) {
      float4 f = *(const float4*)(W + (size_t)idx * 4);
      ushort4 o;
      o.x = f2bf(f.x); o.y = f2bf(f.y); o.z = f2bf(f.z); o.w = f2bf(f.w);
      *(ushort4*)(Wb + (size_t)idx * 4) = o;
    }
    return;
  }
  // ---- layout (single block, r2-verified) ----
  __shared__ double s_wsum[16];
  __shared__ double s_avg;
  __shared__ int s_cnt[1024];
  float v = (tid < P) ? iw[tid] : 0.0f;
  double d = (double)v;
#pragma unroll
  for (int off = 32; off > 0; off >>= 1) d += __shfl_down(d, off, 64);
  if ((tid & 63) == 0) s_wsum[tid >> 6] = d;
  __syncthreads();
  if (tid == 0) {
    double s = 0.0;
    for (int i = 0; i < 16; ++i) s += s_wsum[i];
    s_avg = s / (double)P;
  }
  __syncthreads();
  int cnt = 0, sz = 32;
  if (tid < P) {
    double val = 32.0 * pow(s_avg / (double)v, 0.05);
    if (val > 32.0) val = 32.0;
    sz = (val >= 24.0) ? 32 : (val >= 12.0) ? 16 : (val >= 6.0) ? 8 : 4;
    cnt = (sz < 32) ? (32 / sz) : 1;
  }
  s_cnt[tid] = cnt;
  __syncthreads();
  for (int dl = 1; dl < 1024; dl <<= 1) {
    int add = (tid >= dl) ? s_cnt[tid - dl] : 0;
    __syncthreads();
    s_cnt[tid] += add;
    __syncthreads();
  }
  if (tid < P) {
    int off = s_cnt[tid] - cnt;
    int ini_col = (tid * 32) & 1023;
    int ini_row = (tid * 32 * 32) >> 10;
    if (sz == 32) {
      tokBase[off] = ini_row * 1024 + ini_col;
      tokMask[off] = 31;
    } else {
      int ns = 32 / sz;
      for (int j = 0; j < ns; ++j) {
        int r = ini_row + (j * sz) / ns;
        int c = ini_col + ((j * sz) & 31);
        tokBase[off + j] = r * 1024 + c;
        tokMask[off + j] = sz - 1;
      }
    }
  }
  // ---- per-output-row tables for fused gemm A-staging ----
  __syncthreads();
  int Ttot = s_cnt[1023];                 // total tokens (inclusive scan tail)
  int MT = nB * Ttot;
  for (int m = tid; m < Mpad; m += 1024) {
    if (m < MT) {
      int bb = m / Ttot;
      int tt = m - bb * Ttot;
      rowBase[m] = bb * 3145728 + tokBase[tt];
      rowMask[m] = tokMask[tt];
    } else {
      rowBase[m] = 0;                     // pad rows: read x[0..], harmless
      rowMask[m] = 31;
    }
  }
}

// -- gemm: 192x128 x BK64, 8 waves, 3-buf, fused A-gather reg-staging ---------
__global__ __launch_bounds__(512)
void gemm_kernel(const float* __restrict__ x,
                 const int* __restrict__ rowBase,
                 const int* __restrict__ rowMask,
                 const unsigned short* __restrict__ Wb,
                 const float* __restrict__ bias, float* __restrict__ out, int Mtot) {
  // per buf: A 192x64 (24 KB) shorts [0,12288), B 128x64 (16 KB) [12288,20480).
  // row = 128 B = 8 chunks of 16 B; chunk c of row r stored at slot c^(r&7).
  // B: swizzle in GLOBAL src addr (gll dst linear). A: explicit swizzled
  // ds_write (reg-staged). Read side (^r7) identical to r8-r12.
  __shared__ unsigned short lds[3][20480];   // 120 KB
  int tid = threadIdx.x;
  int lane = tid & 63;
  int wave = tid >> 6;                       // 0..7
  int wrM = wave >> 1, wrN = wave & 1;       // wave tile 48x64

  // bijective XCD-chunked swizzle (m204), 252 blocks.
  int lin = blockIdx.x;
  int nwg = gridDim.x;                       // 252
  int q8 = nwg >> 3, r8 = nwg & 7;           // 31, 4
  int xcd = lin & 7, slot = lin >> 3;
  int wg = (xcd < r8) ? xcd * (q8 + 1) + slot
                      : r8 * (q8 + 1) + (xcd - r8) * q8 + slot;
  int mBase = (wg / 6) * BM;
  int nBase = (wg % 6) * BN;

  f32x4 acc[3][4] = {};

  int lrow = lane >> 3;
  int fo = (lane & 7) * 8;                   // k-local start of this lane's chunk
  int schunk = (lane & 7) ^ lrow;            // swizzled chunk slot / B src chunk

  // B staging: rows wave*16 + inst*8 + lrow (2 gll insts), pre-swizzled source.
  const unsigned short* Bg = Wb + (size_t)(nBase + wave * 16 + lrow) * K_DIM + schunk * 8;
  unsigned short* Bdst0 = &lds[0][12288 + (wave * 16) * 64] + lane * 8;   // +inst*512

  // A row tables: rows wave*24 + i*8 + lrow (i=0..2), fixed across all tiles.
  int rbase[3], rmask[3], rsh[3];
#pragma unroll
  for (int i = 0; i < 3; ++i) {
    int m = mBase + wave * 24 + i * 8 + lrow;
    rbase[i] = rowBase[m];
    rmask[i] = rowMask[m];
    rsh[i]   = __popc(rmask[i]);
  }
  int AldsOff = (wave * 24 + lrow) * 64 + schunk * 8;   // shorts; +i*512

  float4 aq[3][2];                           // in-flight A f32 (1 tile)

#define STAGE_B(BUF, KOFF)                                                  \
    _Pragma("unroll")                                                       \
    for (int inst = 0; inst < 2; ++inst)                                    \
      gload16(Bg + (size_t)(inst * 8) * K_DIM + (KOFF),                     \
              Bdst0 + (size_t)(BUF) * 20480 + inst * 512);

  // chunk covers k = KOFF + (lane&7)*8 + e, e=0..7; f=k&1023 (no carry:
  // KOFF%64==0, fo<64); h=(f>>sh)&mask, w=f&mask; e0..3 and e4..7 are each
  // one contiguous float4 (f%8==0 => w%sz in {0,..}; h const per quad).
#define AISSUE(KOFF)                                                        \
  {                                                                         \
    int f0 = ((KOFF) & 1023) + fo;                                          \
    int c3 = (KOFF) >> 10;                                                  \
    _Pragma("unroll")                                                       \
    for (int i = 0; i < 3; ++i) {                                           \
      int h0 = (f0 >> rsh[i]) & rmask[i];                                   \
      int w0 = f0 & rmask[i];                                               \
      int h1 = ((f0 + 4) >> rsh[i]) & rmask[i];                             \
      int w1 = (f0 + 4) & rmask[i];                                         \
      const float* p = x + (size_t)(rbase[i] + (c3 << 20));                 \
      aq[i][0] = *(const float4*)(p + (h0 << 10) + w0);                     \
      aq[i][1] = *(const float4*)(p + (h1 << 10) + w1);                     \
    }                                                                       \
  }

#define ACONV(BUF)                                                          \
  {                                                                         \
    _Pragma("unroll")                                                       \
    for (int i = 0; i < 3; ++i) {                                           \
      uint4 v;                                                              \
      v.x = pk2(aq[i][0].x, aq[i][0].y);                                    \
      v.y = pk2(aq[i][0].z, aq[i][0].w);                                    \
      v.z = pk2(aq[i][1].x, aq[i][1].y);                                    \
      v.w = pk2(aq[i][1].z, aq[i][1].w);                                    \
      *(uint4*)&lds[BUF][AldsOff + i * 512] = v;                            \
    }                                                                       \
  }

  int rr = lane & 15, q = lane >> 4;
  int r7 = rr & 7;

#define FRAGS(BUF, KH)                                                      \
    bf16x8 aF[3], bF[4];                                                    \
    _Pragma("unroll")                                                       \
    for (int i = 0; i < 3; ++i)                                             \
      aF[i] = *(const bf16x8*)&lds[BUF][(wrM * 48 + i * 16 + rr) * 64 +     \
                                        (((KH) * 4 + q) ^ r7) * 8];         \
    _Pragma("unroll")                                                       \
    for (int j = 0; j < 4; ++j)                                             \
      bF[j] = *(const bf16x8*)&lds[BUF][12288 +                             \
                                        (wrN * 64 + j * 16 + rr) * 64 +     \
                                        (((KH) * 4 + q) ^ r7) * 8];

#define MF                                                                  \
    asm volatile("s_waitcnt lgkmcnt(0)" ::: "memory");                      \
    __builtin_amdgcn_s_barrier();                                           \
    __builtin_amdgcn_s_setprio(1);                                          \
    _Pragma("unroll")                                                       \
    for (int i = 0; i < 3; ++i)                                             \
      _Pragma("unroll")                                                     \
      for (int j = 0; j < 4; ++j)                                           \
        acc[i][j] = __builtin_amdgcn_mfma_f32_16x16x32_bf16(aF[i], bF[j],   \
                                                            acc[i][j], 0, 0, 0); \
    __builtin_amdgcn_s_setprio(0);

  // tile t (buf t%3): ph0 issues B-gll(t+1)->buf n then A-f32(t+1)->regs;
  // ph1 converts+ds_writes A into buf n (dep-wait drains queue; vmcnt(0)
  // backstop), lgkm(0) pre-barrier retires frag reads + conv writes. WAR:
  // buf n last read at t-2, drained 2 barriers earlier.
#define PH0(BUF, SBUF, KOFF) { FRAGS(BUF, 0) STAGE_B(SBUF, KOFF) AISSUE(KOFF) MF }
#define PH1(BUF, SBUF)                                                      \
  { FRAGS(BUF, 1) ACONV(SBUF)                                               \
    asm volatile("s_waitcnt vmcnt(0)" ::: "memory"); MF }
#define PH0N(BUF) { FRAGS(BUF, 0) MF }
#define PH1N(BUF) { FRAGS(BUF, 1) MF }
#define ITER(BUF, SBUF, KOFF) PH0(BUF, SBUF, KOFF) PH1(BUF, SBUF)

  // prologue: stage tile 0 (B gll + A reg-convert), drain, barrier.
  STAGE_B(0, 0)
  AISSUE(0)
  ACONV(0)
  asm volatile("s_waitcnt vmcnt(0)" ::: "memory");
  asm volatile("s_waitcnt lgkmcnt(0)" ::: "memory");
  __builtin_amdgcn_s_barrier();

  for (int g = 0; g < 15; ++g) {             // tiles 0..44 stage 1..45
    int k = g * 192;
    ITER(0, 1, k + 64)
    ITER(1, 2, k + 128)
    ITER(2, 0, k + 192)
  }
  ITER(0, 1, 2944)                           // tile 45, stage 46 -> buf1
  ITER(1, 2, 3008)                           // tile 46, stage 47 -> buf2
  PH0N(2) PH1N(2)                            // tile 47
#undef ITER
#undef PH0
#undef PH1
#undef PH0N
#undef PH1N
#undef MF
#undef FRAGS
#undef ACONV
#undef AISSUE
#undef STAGE_B

  // epilogue: C/D layout col=lane&15, row=(lane>>4)*4+reg (r2-verified)
#pragma unroll
  for (int j = 0; j < 4; ++j) {
    int n = nBase + wrN * 64 + j * 16 + rr;
    float bv = bias[n];
#pragma unroll
    for (int i = 0; i < 3; ++i) {
      int mrow = mBase + wrM * 48 + i * 16 + q * 4;
#pragma unroll
      for (int r2 = 0; r2 < 4; ++r2) {
        int m = mrow + r2;
        if (m < Mtot) out[(size_t)m * N_DIM + n] = acc[i][j][r2] + bv;
      }
    }
  }
}

extern "C" void kernel_launch(void* const* d_in, const int* in_sizes, int n_in,
                              void* d_out, int out_size, void* d_ws, size_t ws_size,
                              hipStream_t stream) {
  const float* x  = (const float*)d_in[0];
  const float* iw = (const float*)d_in[1];
  const float* W  = (const float*)d_in[2];
  const float* b  = (const float*)d_in[3];
  int P = in_sizes[1];                        // 992
  int B = in_sizes[0] / (3 * 1024 * 1024);    // 8
  int E = in_sizes[3];                        // 768
  int T = out_size / (B * E);                 // 995
  int Mtot = B * T;                           // 7960
  int mTiles = (Mtot + BM - 1) / BM;          // 42
  int Mpad = mTiles * BM;                     // 8064

  char* ws = (char*)d_ws;
  int* tokBase = (int*)ws;                              // 32 KB
  int* tokMask = (int*)(ws + 32768);                    // 32 KB
  int* rowBase = (int*)(ws + 65536);                    // 32 KB
  int* rowMask = (int*)(ws + 98304);                    // 32 KB
  unsigned short* Wb = (unsigned short*)(ws + 131072);  // 4.72 MB row-major

  int w4 = E * K_DIM / 4;                     // 589824
  int NB_W = (w4 + 1023) / 1024;              // 576
  prep_kernel<<<NB_W + 1, 1024, 0, stream>>>(W, Wb, w4, iw, P, tokBase, tokMask,
                                             rowBase, rowMask, B, Mpad, NB_W);

  dim3 grid((N_DIM / BN) * mTiles);           // 6*42 = 252 blocks, 1D for swizzle
  gemm_kernel<<<grid, 512, 0, stream>>>(x, rowBase, rowMask, Wb, b,
                                        (float*)d_out, Mtot);
}

// Round 7
// 259.285 us; speedup vs baseline: 1.0002x; 1.0002x over previous
//
#include <hip/hip_runtime.h>

// PatchEmbedding2 on MI355X — round 14.
// r13 post-mortem: fused A-gather regressed (gemm 132us, MfmaUtil 11%) — pure
// latency exposure; scattered x-loads had ~60cyc of MFMA cover vs ~500cyc
// latency, 1 block/CU = no one to hide it. REVERT to r12 split pipeline.
// r11-r13 isolate the core disease: at 1 blk/CU, barrier/drain stalls are
// unfillable. Fix: split-K2 — same BM192xBN128, each block does K/2 (24
// tiles), grid 504 = 252 CU x 2 co-resident blocks (2-buf 80KB LDS; 2x80 =
// 160KB exact). Partner block's MFMAs fill this block's vmcnt(0) drains
// (r9-style depth-1, simple ledger). Epilogue: unsafeAtomicAdd f32 (native
// global_atomic_add_f32) onto hipMemsetAsync-zeroed out; kh==0 adds bias.
// Swizzle: 504%8==0 -> simple (lin%8)*63+lin/8 bijective; work order
// m-major/(kh,n) so same-XCD blocks share A half-panels.
// prep/gather: r12 versions (r3/r4-verified).

typedef __attribute__((ext_vector_type(8))) short bf16x8;
typedef __attribute__((ext_vector_type(4))) float f32x4;

#define K_DIM 3072
#define N_DIM 768
#define BM 192
#define BN 128

__device__ __forceinline__ unsigned short f2bf(float f) {
  unsigned int u = __float_as_uint(f);
  u += 0x7fffu + ((u >> 16) & 1u);   // RNE
  return (unsigned short)(u >> 16);
}

__device__ __forceinline__ void gload16(const void* g, void* l) {
  __builtin_amdgcn_global_load_lds(
      (const __attribute__((address_space(1))) void*)g,
      (__attribute__((address_space(3))) void*)l, 16, 0, 0);
}

// ---------------- prep: wconv (row-major) + layout ----------------
__global__ __launch_bounds__(1024)
void prep_kernel(const float* __restrict__ W, unsigned short* __restrict__ Wb, int w4,
                 const float* __restrict__ iw, int P,
                 int* __restrict__ tokBase, int* __restrict__ tokMask, int NB_W) {
  int bid = blockIdx.x;
  int tid = threadIdx.x;
  if (bid < NB_W) {
    int idx = bid * 1024 + tid;
    if (idx < w4) {
      float4 f = *(const float4*)(W + (size_t)idx * 4);
      ushort4 o;
      o.x = f2bf(f.x); o.y = f2bf(f.y); o.z = f2bf(f.z); o.w = f2bf(f.w);
      *(ushort4*)(Wb + (size_t)idx * 4) = o;
    }
    return;
  }
  // ---- layout (single block, r2-verified) ----
  __shared__ double s_wsum[16];
  __shared__ double s_avg;
  __shared__ int s_cnt[1024];
  float v = (tid < P) ? iw[tid] : 0.0f;
  double d = (double)v;
#pragma unroll
  for (int off = 32; off > 0; off >>= 1) d += __shfl_down(d, off, 64);
  if ((tid & 63) == 0) s_wsum[tid >> 6] = d;
  __syncthreads();
  if (tid == 0) {
    double s = 0.0;
    for (int i = 0; i < 16; ++i) s += s_wsum[i];
    s_avg = s / (double)P;
  }
  __syncthreads();
  int cnt = 0, sz = 32;
  if (tid < P) {
    double val = 32.0 * pow(s_avg / (double)v, 0.05);
    if (val > 32.0) val = 32.0;
    sz = (val >= 24.0) ? 32 : (val >= 12.0) ? 16 : (val >= 6.0) ? 8 : 4;
    cnt = (sz < 32) ? (32 / sz) : 1;
  }
  s_cnt[tid] = cnt;
  __syncthreads();
  for (int dl = 1; dl < 1024; dl <<= 1) {
    int add = (tid >= dl) ? s_cnt[tid - dl] : 0;
    __syncthreads();
    s_cnt[tid] += add;
    __syncthreads();
  }
  if (tid < P) {
    int off = s_cnt[tid] - cnt;
    int ini_col = (tid * 32) & 1023;
    int ini_row = (tid * 32 * 32) >> 10;
    if (sz == 32) {
      tokBase[off] = ini_row * 1024 + ini_col;
      tokMask[off] = 31;
    } else {
      int ns = 32 / sz;
      for (int j = 0; j < ns; ++j) {
        int r = ini_row + (j * sz) / ns;
        int c = ini_col + ((j * sz) & 31);
        tokBase[off + j] = r * 1024 + c;
        tokMask[off + j] = sz - 1;
      }
    }
  }
}

// ---------------- gather: row-major Ab, one block per A row (r3/r4-verified) ---
__global__ __launch_bounds__(256)
void gather_kernel(const float* __restrict__ x,
                   const int* __restrict__ tokBase,
                   const int* __restrict__ tokMask,
                   unsigned short* __restrict__ Ab) {
  int t = blockIdx.x;
  int b = blockIdx.y;
  int T = gridDim.x;
  int m = b * T + t;
  int base = tokBase[t];
  int mask = tokMask[t];
  int sh = __popc(mask);
  const float* xb = x + (size_t)b * 3145728 + (size_t)base;
  unsigned short* arow = Ab + (size_t)m * K_DIM;
#pragma unroll
  for (int it = 0; it < 3; ++it) {
    int g = it * 256 + threadIdx.x;
    int p = g * 4;
    int c = p >> 10;
    int f = p & 1023;
    int h = (f >> sh) & mask;
    int w = f & mask;
    float4 fv = *(const float4*)(xb + (size_t)c * 1048576 + h * 1024 + w);
    ushort4 o;
    o.x = f2bf(fv.x); o.y = f2bf(fv.y); o.z = f2bf(fv.z); o.w = f2bf(fv.w);
    *(ushort4*)(arow + p) = o;
  }
}

// -- gemm: split-K2, 192x128 x BK64, 8 waves, 2-buf 80KB, 2 blocks/CU ---------
__global__ __launch_bounds__(512)
void gemm_kernel(const unsigned short* __restrict__ A, const unsigned short* __restrict__ Wb,
                 const float* __restrict__ bias, float* __restrict__ out, int Mtot) {
  // per buf: A 192x64 (24 KB) shorts [0,12288), B 128x64 (16 KB) [12288,20480).
  // row = 128 B = 8 chunks of 16 B; chunk c of row r stored at slot c^(r&7)
  // (swizzle applied in GLOBAL src addr; gll LDS dst is linear lane*16).
  __shared__ unsigned short lds[2][20480];   // 80 KB -> 2 blocks/CU
  int tid = threadIdx.x;
  int lane = tid & 63;
  int wave = tid >> 6;                       // 0..7
  int wrM = wave >> 1, wrN = wave & 1;       // wave tile 48x64

  // XCD swizzle: nwg=504, 504%8==0 -> (lin&7)*63 + lin>>3 is bijective.
  // work id: m-major, then (kh,n) -> 12 consecutive ids share an A half-panel.
  int lin = blockIdx.x;
  int wg = (lin & 7) * 63 + (lin >> 3);
  int mBase = (wg / 12) * BM;
  int rem = wg % 12;
  int khalf = rem / 6;
  int nBase = (rem % 6) * BN;
  int kStart = khalf * (K_DIM / 2);          // 24 K-tiles of 64

  f32x4 acc[3][4] = {};

  // staging: 5 gll/wave/tile. A: rows wave*24 + inst*8 + lrow (3 insts),
  // B: rows wave*16 + inst*8 + lrow (2 insts). row&7 == lane>>3 == lrow.
  int lrow = lane >> 3;
  int schunk = (lane & 7) ^ lrow;            // pre-swizzled source chunk
  const unsigned short* Ag = A + (size_t)(mBase + wave * 24 + lrow) * K_DIM + schunk * 8;
  const unsigned short* Bg = Wb + (size_t)(nBase + wave * 16 + lrow) * K_DIM + schunk * 8;
  unsigned short* Adst0 = &lds[0][(wave * 24) * 64] + lane * 8;           // +inst*512
  unsigned short* Bdst0 = &lds[0][12288 + (wave * 16) * 64] + lane * 8;   // +inst*512

#define STAGE_A(BUF, KOFF)                                                  \
    _Pragma("unroll")                                                       \
    for (int inst = 0; inst < 3; ++inst)                                    \
      gload16(Ag + (size_t)(inst * 8) * K_DIM + (KOFF),                     \
              Adst0 + (size_t)(BUF) * 20480 + inst * 512);

#define STAGE_B(BUF, KOFF)                                                  \
    _Pragma("unroll")                                                       \
    for (int inst = 0; inst < 2; ++inst)                                    \
      gload16(Bg + (size_t)(inst * 8) * K_DIM + (KOFF),                     \
              Bdst0 + (size_t)(BUF) * 20480 + inst * 512);

  int rr = lane & 15, q = lane >> 4;
  int r7 = rr & 7;

  // phase: {ds_read frags; stage share; [vmcnt]; lgkm(0); barrier; MFMA}.
  // lgkm(0) pre-barrier => reads complete at barrier arrival, so gll writes
  // to the other buf (issued post-release next tile) can't clobber (r12 WAR
  // argument, 2-buf version: stage target buf was last read in the PREVIOUS
  // tile, whose reads drained before its last barrier).
#define PH(BUF, KH, STG, WAITC)                                             \
  {                                                                         \
    bf16x8 aF[3], bF[4];                                                    \
    _Pragma("unroll")                                                       \
    for (int i = 0; i < 3; ++i)                                             \
      aF[i] = *(const bf16x8*)&lds[BUF][(wrM * 48 + i * 16 + rr) * 64 +     \
                                        (((KH) * 4 + q) ^ r7) * 8];         \
    _Pragma("unroll")                                                       \
    for (int j = 0; j < 4; ++j)                                             \
      bF[j] = *(const bf16x8*)&lds[BUF][12288 +                             \
                                        (wrN * 64 + j * 16 + rr) * 64 +     \
                                        (((KH) * 4 + q) ^ r7) * 8];         \
    STG                                                                     \
    WAITC                                                                   \
    asm volatile("s_waitcnt lgkmcnt(0)" ::: "memory");                      \
    __builtin_amdgcn_s_barrier();                                           \
    __builtin_amdgcn_s_setprio(1);                                          \
    _Pragma("unroll")                                                       \
    for (int i = 0; i < 3; ++i)                                             \
      _Pragma("unroll")                                                     \
      for (int j = 0; j < 4; ++j)                                           \
        acc[i][j] = __builtin_amdgcn_mfma_f32_16x16x32_bf16(aF[i], bF[j],   \
                                                            acc[i][j], 0, 0, 0); \
    __builtin_amdgcn_s_setprio(0);                                          \
  }

#define VM0 asm volatile("s_waitcnt vmcnt(0)" ::: "memory");
#define NOP

  // tile t (buf t&1): ph0 stages tile t+1 into buf^1; ph1 drains (VM0) so
  // t+1's data is ready. Drain stall is hidden by the partner block on the CU.
#define ITER(BUF, KOFF)                                                     \
  PH(BUF, 0, STAGE_A(BUF ^ 1, KOFF) STAGE_B(BUF ^ 1, KOFF), NOP)            \
  PH(BUF, 1, NOP, VM0)

  // prologue: stage tile 0, drain, barrier.
  STAGE_A(0, kStart) STAGE_B(0, kStart)
  VM0
  __builtin_amdgcn_s_barrier();

  for (int g = 0; g < 11; ++g) {             // tiles 0..21 stage 1..22
    int k = kStart + g * 128;
    ITER(0, k + 64)
    ITER(1, k + 128)
  }
  ITER(0, kStart + 1472)                     // tile 22, stage 23 -> buf1
  PH(1, 0, NOP, NOP)                         // tile 23
  PH(1, 1, NOP, NOP)
#undef ITER
#undef PH
#undef STAGE_A
#undef STAGE_B
#undef VM0
#undef NOP

  // epilogue: C/D layout col=lane&15, row=(lane>>4)*4+reg (r2-verified).
  // out pre-zeroed; atomic f32 add merges the two K-halves; kh0 adds bias.
#pragma unroll
  for (int j = 0; j < 4; ++j) {
    int n = nBase + wrN * 64 + j * 16 + rr;
    float bv = (khalf == 0) ? bias[n] : 0.0f;
#pragma unroll
    for (int i = 0; i < 3; ++i) {
      int mrow = mBase + wrM * 48 + i * 16 + q * 4;
#pragma unroll
      for (int r2 = 0; r2 < 4; ++r2) {
        int m = mrow + r2;
        if (m < Mtot) unsafeAtomicAdd(&out[(size_t)m * N_DIM + n],
                                      acc[i][j][r2] + bv);
      }
    }
  }
}

extern "C" void kernel_launch(void* const* d_in, const int* in_sizes, int n_in,
                              void* d_out, int out_size, void* d_ws, size_t ws_size,
                              hipStream_t stream) {
  const float* x  = (const float*)d_in[0];
  const float* iw = (const float*)d_in[1];
  const float* W  = (const float*)d_in[2];
  const float* b  = (const float*)d_in[3];
  int P = in_sizes[1];                        // 992
  int B = in_sizes[0] / (3 * 1024 * 1024);    // 8
  int E = in_sizes[3];                        // 768
  int T = out_size / (B * E);                 // 995
  int Mtot = B * T;                           // 7960
  int mTiles = (Mtot + BM - 1) / BM;          // 42

  char* ws = (char*)d_ws;
  int* tokBase = (int*)ws;                              // 32 KB
  int* tokMask = (int*)(ws + 32768);                    // 32 KB
  unsigned short* Wb = (unsigned short*)(ws + 65536);   // 4.72 MB row-major
  unsigned short* Ab = (unsigned short*)(ws + 65536 + (size_t)E * K_DIM * 2);

  // zero out for the atomic split-K merge (independent of prep/gather).
  hipMemsetAsync(d_out, 0, (size_t)out_size * sizeof(float), stream);

  int w4 = E * K_DIM / 4;                     // 589824
  int NB_W = (w4 + 1023) / 1024;              // 576
  prep_kernel<<<NB_W + 1, 1024, 0, stream>>>(W, Wb, w4, iw, P, tokBase, tokMask, NB_W);

  dim3 gGrid(T, B);
  gather_kernel<<<gGrid, 256, 0, stream>>>(x, tokBase, tokMask, Ab);

  // pad rows [Mtot, 8064) of Ab never written; epilogue guards m < Mtot.

  dim3 grid((N_DIM / BN) * mTiles * 2);       // 6*42*2 = 504 blocks (split-K2)
  gemm_kernel<<<grid, 512, 0, stream>>>(Ab, Wb, b, (float*)d_out, Mtot);
}

// Round 8
// 224.966 us; speedup vs baseline: 1.1528x; 1.1526x over previous
//
#include <hip/hip_runtime.h>

// PatchEmbedding2 on MI355X — round 15 (recovery).
// r14 post-mortem: split-K2 regressed (83us): depth-1 VM0 ledger exposed
// ~400cyc/tile AND 12.4M scalar f32 atomics (WRITE_SIZE 24->47.7MB) added a
// serial tail; VALUBusy 21->8.4% = waiting, not working. REVERT to r11 (best
// measured: 224.79us).
// Flat-spot analysis across r7-r14: per-CU LDS traffic x achieved us/MB is
// ~constant over the whole explored design space (r9: 10.35MB@6.1 -> 63us;
// r12: 7.3MB@7.1 -> 52us; best unexplored variant models to ~49us). Gather is
// AT the HBM roofline (25us vs 23.5 floor). Fills (118us @85% HBM) + gaps
// (~25us) are harness-fixed. gemm ~52us is the structure flat-spot.
// One safe micro-fix vs r11: epilogue m<Mtot guard hoisted — only the last
// m-tile (mBase=7872) needs it; 41/42 blocks take an unguarded store path.
// Everything else byte-identical to r11.

typedef __attribute__((ext_vector_type(8))) short bf16x8;
typedef __attribute__((ext_vector_type(4))) float f32x4;

#define K_DIM 3072
#define N_DIM 768
#define BM 192
#define BN 128

__device__ __forceinline__ unsigned short f2bf(float f) {
  unsigned int u = __float_as_uint(f);
  u += 0x7fffu + ((u >> 16) & 1u);   // RNE
  return (unsigned short)(u >> 16);
}

__device__ __forceinline__ void gload16(const void* g, void* l) {
  __builtin_amdgcn_global_load_lds(
      (const __attribute__((address_space(1))) void*)g,
      (__attribute__((address_space(3))) void*)l, 16, 0, 0);
}

// ---------------- prep: wconv (row-major) + layout ----------------
__global__ __launch_bounds__(1024)
void prep_kernel(const float* __restrict__ W, unsigned short* __restrict__ Wb, int w4,
                 const float* __restrict__ iw, int P,
                 int* __restrict__ tokBase, int* __restrict__ tokMask, int NB_W) {
  int bid = blockIdx.x;
  int tid = threadIdx.x;
  if (bid < NB_W) {
    int idx = bid * 1024 + tid;
    if (idx < w4) {
      float4 f = *(const float4*)(W + (size_t)idx * 4);
      ushort4 o;
      o.x = f2bf(f.x); o.y = f2bf(f.y); o.z = f2bf(f.z); o.w = f2bf(f.w);
      *(ushort4*)(Wb + (size_t)idx * 4) = o;
    }
    return;
  }
  // ---- layout (single block, r2-verified) ----
  __shared__ double s_wsum[16];
  __shared__ double s_avg;
  __shared__ int s_cnt[1024];
  float v = (tid < P) ? iw[tid] : 0.0f;
  double d = (double)v;
#pragma unroll
  for (int off = 32; off > 0; off >>= 1) d += __shfl_down(d, off, 64);
  if ((tid & 63) == 0) s_wsum[tid >> 6] = d;
  __syncthreads();
  if (tid == 0) {
    double s = 0.0;
    for (int i = 0; i < 16; ++i) s += s_wsum[i];
    s_avg = s / (double)P;
  }
  __syncthreads();
  int cnt = 0, sz = 32;
  if (tid < P) {
    double val = 32.0 * pow(s_avg / (double)v, 0.05);
    if (val > 32.0) val = 32.0;
    sz = (val >= 24.0) ? 32 : (val >= 12.0) ? 16 : (val >= 6.0) ? 8 : 4;
    cnt = (sz < 32) ? (32 / sz) : 1;
  }
  s_cnt[tid] = cnt;
  __syncthreads();
  for (int dl = 1; dl < 1024; dl <<= 1) {
    int add = (tid >= dl) ? s_cnt[tid - dl] : 0;
    __syncthreads();
    s_cnt[tid] += add;
    __syncthreads();
  }
  if (tid < P) {
    int off = s_cnt[tid] - cnt;
    int ini_col = (tid * 32) & 1023;
    int ini_row = (tid * 32 * 32) >> 10;
    if (sz == 32) {
      tokBase[off] = ini_row * 1024 + ini_col;
      tokMask[off] = 31;
    } else {
      int ns = 32 / sz;
      for (int j = 0; j < ns; ++j) {
        int r = ini_row + (j * sz) / ns;
        int c = ini_col + ((j * sz) & 31);
        tokBase[off + j] = r * 1024 + c;
        tokMask[off + j] = sz - 1;
      }
    }
  }
}

// ---------------- gather: row-major Ab, one block per A row (r3/r4-verified) ---
__global__ __launch_bounds__(256)
void gather_kernel(const float* __restrict__ x,
                   const int* __restrict__ tokBase,
                   const int* __restrict__ tokMask,
                   unsigned short* __restrict__ Ab) {
  int t = blockIdx.x;
  int b = blockIdx.y;
  int T = gridDim.x;
  int m = b * T + t;
  int base = tokBase[t];
  int mask = tokMask[t];
  int sh = __popc(mask);
  const float* xb = x + (size_t)b * 3145728 + (size_t)base;
  unsigned short* arow = Ab + (size_t)m * K_DIM;
#pragma unroll
  for (int it = 0; it < 3; ++it) {
    int g = it * 256 + threadIdx.x;
    int p = g * 4;
    int c = p >> 10;
    int f = p & 1023;
    int h = (f >> sh) & mask;
    int w = f & mask;
    float4 fv = *(const float4*)(xb + (size_t)c * 1048576 + h * 1024 + w);
    ushort4 o;
    o.x = f2bf(fv.x); o.y = f2bf(fv.y); o.z = f2bf(fv.z); o.w = f2bf(fv.w);
    *(ushort4*)(arow + p) = o;
  }
}

// -- gemm: 192x128 x BK64, 8 waves, 3-buf depth-2, 2-phase/tile + setprio -----
__global__ __launch_bounds__(512)
void gemm_kernel(const unsigned short* __restrict__ A, const unsigned short* __restrict__ Wb,
                 const float* __restrict__ bias, float* __restrict__ out, int Mtot) {
  // per buf: A 192x64 (24 KB) shorts [0,12288), B 128x64 (16 KB) [12288,20480).
  // row = 128 B = 8 chunks of 16 B; chunk c of row r stored at slot c^(r&7)
  // (swizzle applied in GLOBAL src addr; gll LDS dst is linear lane*16).
  __shared__ unsigned short lds[3][20480];   // 120 KB
  int tid = threadIdx.x;
  int lane = tid & 63;
  int wave = tid >> 6;                       // 0..7
  int wrM = wave >> 1, wrN = wave & 1;       // wave tile 48x64 at (wrM*48, wrN*64)

  // bijective XCD-chunked swizzle (m204), 252 blocks.
  int lin = blockIdx.x;
  int nwg = gridDim.x;                       // 252
  int q8 = nwg >> 3, r8 = nwg & 7;           // 31, 4
  int xcd = lin & 7, slot = lin >> 3;
  int wg = (xcd < r8) ? xcd * (q8 + 1) + slot
                      : r8 * (q8 + 1) + (xcd - r8) * q8 + slot;
  int mBase = (wg / 6) * BM;
  int nBase = (wg % 6) * BN;

  f32x4 acc[3][4] = {};

  // staging: uniform 5 gll/wave/tile. A: rows wave*24 + inst*8 + lrow (3 insts)
  // B: rows wave*16 + inst*8 + lrow (2 insts). 24,16,48,64 all ≡0 mod 8 so
  // row&7 == lane>>3 == lrow always; source chunk pre-swizzled (lane&7)^lrow.
  int lrow = lane >> 3;
  int schunk = (lane & 7) ^ lrow;
  const unsigned short* Ag = A + (size_t)(mBase + wave * 24 + lrow) * K_DIM + schunk * 8;
  const unsigned short* Bg = Wb + (size_t)(nBase + wave * 16 + lrow) * K_DIM + schunk * 8;
  unsigned short* Adst0 = &lds[0][(wave * 24) * 64] + lane * 8;           // +inst*512
  unsigned short* Bdst0 = &lds[0][12288 + (wave * 16) * 64] + lane * 8;   // +inst*512

#define STAGE_A(BUF, KOFF)                                                  \
    _Pragma("unroll")                                                       \
    for (int inst = 0; inst < 3; ++inst)                                    \
      gload16(Ag + (size_t)(inst * 8) * K_DIM + (KOFF),                     \
              Adst0 + (size_t)(BUF) * 20480 + inst * 512);

#define STAGE_B(BUF, KOFF)                                                  \
    _Pragma("unroll")                                                       \
    for (int inst = 0; inst < 2; ++inst)                                    \
      gload16(Bg + (size_t)(inst * 8) * K_DIM + (KOFF),                     \
              Bdst0 + (size_t)(BUF) * 20480 + inst * 512);

  int rr = lane & 15, q = lane >> 4;
  int r7 = rr & 7;

  // one phase: ds_read this phase's frags, issue share of next-next-tile
  // stage, optional counted vmcnt, barrier, lgkmcnt(0)+sched_barrier (rule
  // 18), prio-wrapped 12 MFMA, barrier.
#define PH(BUF, KH, STG, WAITC)                                             \
  {                                                                         \
    bf16x8 aF[3], bF[4];                                                    \
    _Pragma("unroll")                                                       \
    for (int i = 0; i < 3; ++i)                                             \
      aF[i] = *(const bf16x8*)&lds[BUF][(wrM * 48 + i * 16 + rr) * 64 +     \
                                        (((KH) * 4 + q) ^ r7) * 8];         \
    _Pragma("unroll")                                                       \
    for (int j = 0; j < 4; ++j)                                             \
      bF[j] = *(const bf16x8*)&lds[BUF][12288 +                             \
                                        (wrN * 64 + j * 16 + rr) * 64 +     \
                                        (((KH) * 4 + q) ^ r7) * 8];         \
    STG                                                                     \
    WAITC                                                                   \
    __builtin_amdgcn_s_barrier();                                           \
    asm volatile("s_waitcnt lgkmcnt(0)" ::: "memory");                      \
    __builtin_amdgcn_sched_barrier(0);                                      \
    __builtin_amdgcn_s_setprio(1);                                          \
    _Pragma("unroll")                                                       \
    for (int i = 0; i < 3; ++i)                                             \
      _Pragma("unroll")                                                     \
      for (int j = 0; j < 4; ++j)                                           \
        acc[i][j] = __builtin_amdgcn_mfma_f32_16x16x32_bf16(aF[i], bF[j],   \
                                                            acc[i][j], 0, 0, 0); \
    __builtin_amdgcn_s_setprio(0);                                          \
    __builtin_amdgcn_s_barrier();                                           \
  }

#define VM5 asm volatile("s_waitcnt vmcnt(5)" ::: "memory");
#define VM0 asm volatile("s_waitcnt vmcnt(0)" ::: "memory");
#define NOP

  // iter t (buf t%3): phase0 stages A of tile t+2, phase1 stages B of t+2
  // then waits vmcnt(5) => tile t+1's 5 landed before next iter's ds_reads.
#define ITER(BUF, SBUF, KOFF)                                               \
  PH(BUF, 0, STAGE_A(SBUF, KOFF), NOP)                                      \
  PH(BUF, 1, STAGE_B(SBUF, KOFF), VM5)

  // prologue: stage tiles 0,1; wait tile 0 landed (10 outstanding -> vmcnt(5))
  STAGE_A(0, 0) STAGE_B(0, 0)
  STAGE_A(1, 64) STAGE_B(1, 64)
  VM5
  __builtin_amdgcn_s_barrier();

  for (int g = 0; g < 15; ++g) {             // tiles 0..44
    int k = g * 192;
    ITER(0, 2, k + 128)
    ITER(1, 0, k + 192)
    ITER(2, 1, k + 256)
  }
  // tile 45 (buf0): stages tile 47 into buf2
  ITER(0, 2, 3008)
  // tile 46 (buf1): nothing to stage; need tile 47 landed at end
  PH(1, 0, NOP, NOP)
  PH(1, 1, NOP, VM0)
  // tile 47 (buf2): drained
  PH(2, 0, NOP, NOP)
  PH(2, 1, NOP, NOP)
#undef ITER
#undef PH
#undef STAGE_A
#undef STAGE_B
#undef VM5
#undef VM0
#undef NOP

  // epilogue: C/D layout col=lane&15, row=(lane>>4)*4+reg (r2-verified).
  // Guard hoisted: only the last m-tile (mBase+BM > Mtot) needs per-row checks.
  if (mBase + BM <= Mtot) {
#pragma unroll
    for (int j = 0; j < 4; ++j) {
      int n = nBase + wrN * 64 + j * 16 + rr;
      float bv = bias[n];
#pragma unroll
      for (int i = 0; i < 3; ++i) {
        int mrow = mBase + wrM * 48 + i * 16 + q * 4;
#pragma unroll
        for (int r2 = 0; r2 < 4; ++r2)
          out[(size_t)(mrow + r2) * N_DIM + n] = acc[i][j][r2] + bv;
      }
    }
  } else {
#pragma unroll
    for (int j = 0; j < 4; ++j) {
      int n = nBase + wrN * 64 + j * 16 + rr;
      float bv = bias[n];
#pragma unroll
      for (int i = 0; i < 3; ++i) {
        int mrow = mBase + wrM * 48 + i * 16 + q * 4;
#pragma unroll
        for (int r2 = 0; r2 < 4; ++r2) {
          int m = mrow + r2;
          if (m < Mtot) out[(size_t)m * N_DIM + n] = acc[i][j][r2] + bv;
        }
      }
    }
  }
}

extern "C" void kernel_launch(void* const* d_in, const int* in_sizes, int n_in,
                              void* d_out, int out_size, void* d_ws, size_t ws_size,
                              hipStream_t stream) {
  const float* x  = (const float*)d_in[0];
  const float* iw = (const float*)d_in[1];
  const float* W  = (const float*)d_in[2];
  const float* b  = (const float*)d_in[3];
  int P = in_sizes[1];                        // 992
  int B = in_sizes[0] / (3 * 1024 * 1024);    // 8
  int E = in_sizes[3];                        // 768
  int T = out_size / (B * E);                 // 995
  int Mtot = B * T;                           // 7960
  int mTiles = (Mtot + BM - 1) / BM;          // 42 (42*192 = 8064)

  char* ws = (char*)d_ws;
  int* tokBase = (int*)ws;                              // 32 KB
  int* tokMask = (int*)(ws + 32768);                    // 32 KB
  unsigned short* Wb = (unsigned short*)(ws + 65536);   // 4.72 MB row-major
  unsigned short* Ab = (unsigned short*)(ws + 65536 + (size_t)E * K_DIM * 2);

  int w4 = E * K_DIM / 4;                     // 589824
  int NB_W = (w4 + 1023) / 1024;              // 576
  prep_kernel<<<NB_W + 1, 1024, 0, stream>>>(W, Wb, w4, iw, P, tokBase, tokMask, NB_W);

  dim3 gGrid(T, B);
  gather_kernel<<<gGrid, 256, 0, stream>>>(x, tokBase, tokMask, Ab);

  // pad rows [Mtot, 8064) of Ab are never written; garbage affects only
  // output rows >= Mtot, guarded in the epilogue (matmul rows independent).

  dim3 grid((N_DIM / BN) * mTiles);           // 6*42 = 252 blocks, 1D for swizzle
  gemm_kernel<<<grid, 512, 0, stream>>>(Ab, Wb, b, (float*)d_out, Mtot);
}